// Round 3
// baseline (1353.515 us; speedup 1.0000x reference)
//
#include <hip/hip_runtime.h>
#include <math.h>

#define SLEN 512

typedef _Float16 half8 __attribute__((ext_vector_type(8)));
typedef _Float16 half2v __attribute__((ext_vector_type(2)));
typedef __fp16 fp16x2 __attribute__((ext_vector_type(2)));
typedef float f32x4 __attribute__((ext_vector_type(4)));
typedef unsigned int uint;

union U4H8 { uint4 u; half8 h; };
union UH2 { uint u; half2v v; fp16x2 p; };

static __device__ __forceinline__ uint packh2(float a, float b){
  UH2 x; x.p = __builtin_amdgcn_cvt_pkrtz(a, b); return x.u;
}
static __device__ __forceinline__ float loh(uint u){ UH2 x; x.u=u; return (float)x.v[0]; }
static __device__ __forceinline__ float hih(uint u){ UH2 x; x.u=u; return (float)x.v[1]; }
static __device__ __forceinline__ half8 ld_h8(const uint* p){
  U4H8 x; x.u = *(const uint4*)p; return x.h;
}
static __device__ __forceinline__ float rcpf(float x){ return __builtin_amdgcn_rcpf(x); }
static __device__ __forceinline__ float sigm(float v){ return rcpf(1.0f+__expf(-v)); }
static __device__ __forceinline__ float tanh_f(float v){ return 1.0f - 2.0f*rcpf(__expf(2.0f*v)+1.0f); }
static __device__ __forceinline__ float gelu_exact(float v){
  return 0.5f*v*(1.0f+erff(v*0.7071067811865475f));
}
#define MFMA(a,b,c) __builtin_amdgcn_mfma_f32_16x16x32_f16((a),(b),(c),0,0,0)

// LDS-visibility-only workgroup barrier: does NOT drain vmcnt, so global
// stores issued before it stay in flight (unlike __syncthreads, which emits
// s_waitcnt vmcnt(0) and puts an HBM round-trip on the critical path).
static __device__ __forceinline__ void wg_barrier(){
  __builtin_amdgcn_sched_barrier(0);
  asm volatile("s_waitcnt lgkmcnt(0)" ::: "memory");
  __builtin_amdgcn_s_barrier();
  __builtin_amdgcn_sched_barrier(0);
}

// ---------------------------------------------------------------------------
// Per-sample precompute: x_enc -> h0[b,128], x_gx[b,384] (+b_ih, +b_hh r/z), yx[b,128] (+yb1)
// ---------------------------------------------------------------------------
__global__ void k_sample(const float* __restrict__ x, const float* __restrict__ xW, const float* __restrict__ xb,
                         const float* __restrict__ h0W, const float* __restrict__ h0b,
                         const float* __restrict__ W_ih, const float* __restrict__ b_ih, const float* __restrict__ b_hh,
                         const float* __restrict__ yW1, const float* __restrict__ yb1,
                         float* __restrict__ w_h0, float* __restrict__ w_xgx, float* __restrict__ w_yx)
{
  const int b = blockIdx.x, tid = threadIdx.x;   // 384 threads
  __shared__ float sx[128];
  __shared__ float sxe[128];
  if (tid < 128) sx[tid] = x[b*128+tid];
  __syncthreads();
  if (tid < 128) {
    float acc = xb[tid];
    #pragma unroll 8
    for (int j=0;j<128;++j) acc += xW[tid*128+j]*sx[j];
    sxe[tid] = acc;
  }
  __syncthreads();
  {
    const int o = tid;
    float acc = b_ih[o] + (o < 256 ? b_hh[o] : 0.f);   // fold b_hh for r,z only
    #pragma unroll 8
    for (int j=0;j<128;++j) acc += W_ih[o*177+j]*sxe[j];
    w_xgx[b*384+o] = acc;
  }
  if (tid < 128) {
    float acc = h0b[tid];
    #pragma unroll 8
    for (int j=0;j<128;++j) acc += h0W[tid*128+j]*sxe[j];
    w_h0[b*128+tid] = tanhf(acc);
    float a2 = yb1[tid];
    #pragma unroll 8
    for (int j=0;j<128;++j) a2 += yW1[tid*304+128+j]*sxe[j];
    w_yx[b*128+tid] = a2;
  }
}

// ---------------------------------------------------------------------------
// MFMA recurrence. 64 WGs x 384 thr (6 waves), 16 samples per WG.
// waves: 0,1 = r-gate (row halves), 2,3 = z, 4,5 = n.
// In-loop barriers are lgkm-only (wg_barrier): h16/o_h global stores stay in
// flight across steps instead of draining vmcnt(0) on the serial path.
// ---------------------------------------------------------------------------
__global__ __launch_bounds__(384,1) void k_recur(
  const float* __restrict__ W_hh, const float* __restrict__ W_ih, const float* __restrict__ b_hh,
  const int* __restrict__ a, const int* __restrict__ tt,
  const float* __restrict__ yy, const float* __restrict__ mask,
  const float* __restrict__ w_h0, const float* __restrict__ w_xgx,
  const float* __restrict__ a_emb, const float* __restrict__ t_emb,
  float* __restrict__ o_h, uint* __restrict__ h16)
{
  const int tid = threadIdx.x;
  const int wv = tid>>6, lane = tid&63, q = lane>>4, c = lane&15;
  const int g = wv>>1, H = wv&1;       // gate 0=r,1=z,2=n ; row half
  const int b0 = blockIdx.x*16;
  const int rowbase = g*128 + H*64;

  __shared__ __align__(16) uint s_h[2][16*68];     // h f16 [sample][k/2], pad
  __shared__ __align__(16) uint s_ext[2][16*36];   // [ae|te|y|0] f16 per sample
  __shared__ __align__(16) uint s_rz[2][1024];     // r-hat, z-hat f16 pairs
  __shared__ __align__(16) uint s_chunk[2][1024];  // [arr(a,t,y,m)][sample][16 steps]
  __shared__ __align__(16) uint s_al[1600];        // a_emb packed f16 [100][16]
  __shared__ __align__(16) uint s_te[32];          // t_emb packed f16 [4][8]

  // ---- stationary weight A-frags: wf[t4*6+kt]
  half8 wf[24];
  #pragma unroll
  for (int t4=0;t4<4;++t4) {
    const int row = rowbase + t4*16 + c;
    #pragma unroll
    for (int kt=0;kt<4;++kt) {
      const float4* wp = (const float4*)(W_hh + row*128 + kt*32 + q*8);
      float4 v0 = wp[0], v1 = wp[1];
      half8 hv;
      hv[0]=(_Float16)v0.x; hv[1]=(_Float16)v0.y; hv[2]=(_Float16)v0.z; hv[3]=(_Float16)v0.w;
      hv[4]=(_Float16)v1.x; hv[5]=(_Float16)v1.y; hv[6]=(_Float16)v1.z; hv[7]=(_Float16)v1.w;
      wf[t4*6+kt] = hv;
    }
    #pragma unroll
    for (int kt=4;kt<6;++kt) {
      half8 hv;
      #pragma unroll
      for (int j=0;j<8;++j) {
        int k2 = (kt-4)*32 + q*8 + j;
        float v = (k2 < 49) ? W_ih[row*177 + 128 + k2] : 0.f;
        hv[j] = (_Float16)v;
      }
      wf[t4*6+kt] = hv;
    }
  }
  // xg init (C-layout slots)
  f32x4 xg[4];
  #pragma unroll
  for (int t4=0;t4<4;++t4)
    #pragma unroll
    for (int r=0;r<4;++r)
      xg[t4][r] = w_xgx[(b0+c)*384 + rowbase + t4*16 + q*4 + r];
  // n-wave state
  f32x4 bhh[4]; float hm[16];
  if (g==2) {
    #pragma unroll
    for (int t4=0;t4<4;++t4)
      #pragma unroll
      for (int r=0;r<4;++r) {
        bhh[t4][r] = b_hh[256 + H*64 + t4*16 + q*4 + r];
        hm[t4*4+r] = w_h0[(b0+c)*128 + H*64 + t4*16 + q*4 + r];
      }
  }
  // stage embedding tables (packed f16)
  for (int d = tid; d < 1600; d += 384) {
    int row = d>>4, col = d&15;
    s_al[d] = packh2(a_emb[row*32+2*col], a_emb[row*32+2*col+1]);
  }
  if (tid < 32) {
    int row = tid>>3, col = tid&7;
    s_te[tid] = packh2(t_emb[row*16+2*col], t_emb[row*16+2*col+1]);
  }
  // chunk 0 (wave 0): arr q: 0=a,1=t,2=y,3=mask ; 16 steps per sample
  uint4 cr0, cr1, cr2, cr3;
  if (wv==0) {
    const uint* bp = (q==0) ? (const uint*)a : (q==1) ? (const uint*)tt
                   : (q==2) ? (const uint*)yy : (const uint*)mask;
    const uint4* p = (const uint4*)(bp + (size_t)(b0+c)*512);
    cr0=p[0]; cr1=p[1]; cr2=p[2]; cr3=p[3];
    uint4* dst = (uint4*)&s_chunk[0][q*256 + c*16];
    dst[0]=cr0; dst[1]=cr1; dst[2]=cr2; dst[3]=cr3;
  }
  // h0 -> s_h[0]
  if (g==2) {
    #pragma unroll
    for (int t4=0;t4<4;++t4) {
      int base = c*68 + H*32 + t4*8 + q*2;
      s_h[0][base]   = packh2(hm[t4*4+0], hm[t4*4+1]);
      s_h[0][base+1] = packh2(hm[t4*4+2], hm[t4*4+3]);
    }
  }
  __syncthreads();
  // ext for step 0 (r-waves)
  if (g==0) {
    int av = (int)s_chunk[0][c*16];
    int tv = (int)s_chunk[0][256 + c*16];
    uint yu = s_chunk[0][512 + c*16];
    float yv = __uint_as_float(yu);
    #pragma unroll
    for (int i=0;i<4;++i) {
      int d = H*16 + q*4 + i;
      uint u;
      if (d < 16) u = s_al[av*16 + d];
      else if (d < 24) u = s_te[tv*8 + (d-16)];
      else if (d == 24) u = packh2(yv, 0.f);
      else u = 0u;
      s_ext[0][c*36 + d] = u;
    }
  }
  __syncthreads();

  f32x4 acc[4], acc2[4];   // r/z: acc=gates ; n: acc=acc_h, acc2=acc_x

  for (int s=0; s<SLEN; ++s) {
    const int pb = s&1;
    // ---- B-frags
    half8 hb[4], eb[2];
    #pragma unroll
    for (int kt=0;kt<4;++kt) hb[kt] = ld_h8(&s_h[pb][c*68 + kt*16 + q*4]);
    #pragma unroll
    for (int e=0;e<2;++e)    eb[e]  = ld_h8(&s_ext[pb][c*36 + e*16 + q*4]);

    if (g < 2) {
      // z-waves: store h for step s-1 (buffer (s-1)&1 still stable pre-B1)
      if (g==1 && s>0) {
        const int ob = (s-1)&1;
        const int smp = H*8 + (lane>>3), ch = lane&7;
        const uint* hp = &s_h[ob][smp*68 + ch*8];
        const size_t pr = (size_t)(b0+smp)*SLEN + (s-1);
        if (h16) {
          uint4* hq = (uint4*)(h16 + pr*64 + ch*8);
          hq[0] = *(const uint4*)(hp);
          hq[1] = *(const uint4*)(hp + 4);
        } else {
          float* op = o_h + pr*128 + ch*16;
          #pragma unroll
          for (int i2=0;i2<2;++i2) {
            uint4 u = *(const uint4*)(hp + i2*4);
            float4 f0 = make_float4(loh(u.x), hih(u.x), loh(u.y), hih(u.y));
            float4 f1 = make_float4(loh(u.z), hih(u.z), loh(u.w), hih(u.w));
            *(float4*)(op + i2*8)     = f0;
            *(float4*)(op + i2*8 + 4) = f1;
          }
        }
      }
      #pragma unroll
      for (int t4=0;t4<4;++t4) acc[t4] = xg[t4];
      #pragma unroll
      for (int kt=0;kt<6;++kt) {
        half8 bsel = (kt<4) ? hb[kt] : eb[kt-4];
        #pragma unroll
        for (int t4=0;t4<4;++t4) acc[t4] = MFMA(wf[t4*6+kt], bsel, acc[t4]);
      }
      #pragma unroll
      for (int t4=0;t4<4;++t4)
        #pragma unroll
        for (int pr=0;pr<2;++pr) {
          float s0 = sigm(acc[t4][2*pr]), s1 = sigm(acc[t4][2*pr+1]);
          s_rz[g][(((H*4+t4)*2+pr)*4+q)*16 + c] = packh2(s0, s1);
        }
      // chunk prefetch (wave 0)
      if (wv==0) {
        if ((s&15)==8 && s<490) {
          const int s0n = ((s>>4)+1)*16;
          const uint* bp = (q==0) ? (const uint*)a : (q==1) ? (const uint*)tt
                         : (q==2) ? (const uint*)yy : (const uint*)mask;
          const uint4* p = (const uint4*)(bp + (size_t)(b0+c)*512 + s0n);
          cr0=p[0]; cr1=p[1]; cr2=p[2]; cr3=p[3];
        }
        if ((s&15)==9 && s<491) {
          uint4* dst = (uint4*)&s_chunk[((s>>4)+1)&1][q*256 + c*16];
          dst[0]=cr0; dst[1]=cr1; dst[2]=cr2; dst[3]=cr3;
        }
      }
    } else {
      #pragma unroll
      for (int t4=0;t4<4;++t4) { acc[t4] = bhh[t4]; acc2[t4] = xg[t4]; }
      #pragma unroll
      for (int kt=0;kt<4;++kt)
        #pragma unroll
        for (int t4=0;t4<4;++t4) acc[t4] = MFMA(wf[t4*6+kt], hb[kt], acc[t4]);
      #pragma unroll
      for (int kt=4;kt<6;++kt)
        #pragma unroll
        for (int t4=0;t4<4;++t4) acc2[t4] = MFMA(wf[t4*6+kt], eb[kt-4], acc2[t4]);
    }
    wg_barrier();   // B1 (lgkm-only)
    if (g==2) {
      const float mval = __uint_as_float(s_chunk[(s>>4)&1][768 + c*16 + (s&15)]);
      #pragma unroll
      for (int t4=0;t4<4;++t4)
        #pragma unroll
        for (int pr=0;pr<2;++pr) {
          const int slot = (((H*4+t4)*2+pr)*4+q)*16 + c;
          uint ru = s_rz[0][slot], zu = s_rz[1][slot];
          const int i0 = t4*4 + 2*pr;
          float n0 = tanh_f(acc2[t4][2*pr]   + loh(ru)*acc[t4][2*pr]);
          float n1 = tanh_f(acc2[t4][2*pr+1] + hih(ru)*acc[t4][2*pr+1]);
          float h0o = hm[i0], h1o = hm[i0+1];
          float hn0 = n0 + loh(zu)*(h0o - n0);
          float hn1 = n1 + hih(zu)*(h1o - n1);
          hm[i0]   = h0o + mval*(hn0 - h0o);
          hm[i0+1] = h1o + mval*(hn1 - h1o);
        }
      const int nb = (s+1)&1;
      #pragma unroll
      for (int t4=0;t4<4;++t4) {
        int base = c*68 + H*32 + t4*8 + q*2;
        s_h[nb][base]   = packh2(hm[t4*4+0], hm[t4*4+1]);
        s_h[nb][base+1] = packh2(hm[t4*4+2], hm[t4*4+3]);
      }
    } else if (g==0 && s < SLEN-1) {
      const int sn = s+1;
      const int par2 = (sn>>4)&1, st = sn&15;
      int av = (int)s_chunk[par2][c*16 + st];
      int tv = (int)s_chunk[par2][256 + c*16 + st];
      float yv = __uint_as_float(s_chunk[par2][512 + c*16 + st]);
      #pragma unroll
      for (int i=0;i<4;++i) {
        int d = H*16 + q*4 + i;
        uint u;
        if (d < 16) u = s_al[av*16 + d];
        else if (d < 24) u = s_te[tv*8 + (d-16)];
        else if (d == 24) u = packh2(yv, 0.f);
        else u = 0u;
        s_ext[(s+1)&1][c*36 + d] = u;
      }
    }
    wg_barrier();   // B2 (lgkm-only)
  }
  // epilogue: h for s=511
  if (g==1) {
    const int ob = (SLEN-1)&1;
    const int smp = H*8 + (lane>>3), ch = lane&7;
    const uint* hp = &s_h[ob][smp*68 + ch*8];
    const size_t pr = (size_t)(b0+smp)*SLEN + (SLEN-1);
    if (h16) {
      uint4* hq = (uint4*)(h16 + pr*64 + ch*8);
      hq[0] = *(const uint4*)(hp);
      hq[1] = *(const uint4*)(hp + 4);
    } else {
      float* op = o_h + pr*128 + ch*16;
      #pragma unroll
      for (int i2=0;i2<2;++i2) {
        uint4 u = *(const uint4*)(hp + i2*4);
        float4 f0 = make_float4(loh(u.x), hih(u.x), loh(u.y), hih(u.y));
        float4 f1 = make_float4(loh(u.z), hih(u.z), loh(u.w), hih(u.w));
        *(float4*)(op + i2*8)     = f0;
        *(float4*)(op + i2*8 + 4) = f1;
      }
    }
  }
}

// ---------------------------------------------------------------------------
// MFMA heads, wave-pair unit-split (kills VGPR spill). 512 WGs x 256 thr.
// Waves {0,1} = t-head, {2,3} = y-head. Within a pair, wave wv&1 owns 4 of
// the 8 unit-tiles (64 units) -> wf[24] = 96 VGPRs stationary. Every wave
// walks all 64 sample-tiles; the pair shares a parity-double-buffered gelu
// LDS buffer with one lgkm-only barrier per tile (no vmcnt drain of the
// o_h/o_t/o_y stores). h B-frags load straight from global (f16 ws path).
// ---------------------------------------------------------------------------
template<bool H16>
__global__ __launch_bounds__(256,2) void k_heads(
  const float* __restrict__ tW1, const float* __restrict__ tb1,
  const float* __restrict__ tW2, const float* __restrict__ tb2,
  const float* __restrict__ yW1, const float* __restrict__ yW2, const float* __restrict__ yb2,
  const int* __restrict__ a, const int* __restrict__ tt,
  const float* __restrict__ w_yx,
  const float* __restrict__ a_emb, const float* __restrict__ t_emb,
  const float* __restrict__ h_f32, const uint* __restrict__ h16,
  float* __restrict__ o_y, float* __restrict__ o_t, float* __restrict__ o_h)
{
  const int tid = threadIdx.x;
  const int wv = tid>>6, lane = tid&63, q = lane>>4, c = lane&15;
  const bool isY = (wv >= 2);
  const int uh = wv&1;          // unit half (0: units 0-63, 1: 64-127)
  const int pair = wv>>1;       // 0 = t-head pair, 1 = y-head pair
  const int p0 = blockIdx.x*1024;
  const int b0 = blockIdx.x*2;

  __shared__ __align__(16) uint s_al[100*20];      // a_emb packed f16, stride 20
  __shared__ __align__(16) uint s_te[32];          // t_emb packed f16 [4][8]
  __shared__ __align__(16) uint s_gb[2][2][16*68]; // [pair][parity][c*68 + word]

  for (int d = tid; d < 1600; d += 256) {
    int row = d>>4, col = d&15;
    s_al[row*20+col] = packh2(a_emb[row*32+2*col], a_emb[row*32+2*col+1]);
  }
  if (tid < 32) {
    int row = tid>>3, col = tid&7;
    s_te[row*8+col] = packh2(t_emb[row*16+2*col], t_emb[row*16+2*col+1]);
  }

  // ---- stationary first-layer weights: wf[ut*6+kt], unit = uh*64 + ut*16 + c
  half8 wf[24];
  const float* W1 = isY ? yW1 : tW1;
  const int w1stride = isY ? 304 : 128;
  #pragma unroll
  for (int ut=0;ut<4;++ut) {
    const int unit = uh*64 + ut*16 + c;
    #pragma unroll
    for (int kt=0;kt<4;++kt) {
      const float4* wp = (const float4*)(W1 + unit*w1stride + kt*32 + q*8);
      float4 v0 = wp[0], v1 = wp[1];
      half8 hv;
      hv[0]=(_Float16)v0.x; hv[1]=(_Float16)v0.y; hv[2]=(_Float16)v0.z; hv[3]=(_Float16)v0.w;
      hv[4]=(_Float16)v1.x; hv[5]=(_Float16)v1.y; hv[6]=(_Float16)v1.z; hv[7]=(_Float16)v1.w;
      wf[ut*6+kt] = hv;
    }
    #pragma unroll
    for (int kt=4;kt<6;++kt) {
      half8 hv;
      #pragma unroll
      for (int j=0;j<8;++j) {
        int k2 = (kt-4)*32 + q*8 + j;
        float v = (isY && k2 < 48) ? yW1[unit*304 + 256 + k2] : 0.f;
        hv[j] = (_Float16)v;
      }
      wf[ut*6+kt] = hv;
    }
  }
  // ---- second-layer A-frags (full 128-k; layer 2 computed redundantly per pair)
  half8 w2f[4];
  #pragma unroll
  for (int kt=0;kt<4;++kt) {
    half8 hv;
    #pragma unroll
    for (int j=0;j<8;++j) {
      float v = 0.f;
      if (!isY && c < 4) v = tW2[c*128 + kt*32 + q*8 + j];
      if ( isY && c == 0) v = yW2[kt*32 + q*8 + j];
      hv[j] = (_Float16)v;
    }
    w2f[kt] = hv;
  }
  float tb2r[4]; float yb2s = yb2[0];
  #pragma unroll
  for (int r=0;r<4;++r) tb2r[r] = tb2[r];

  __syncthreads();

  #pragma unroll 1
  for (int bh=0; bh<2; ++bh) {          // 1024 pairs span exactly 2 samples
    f32x4 bsr[4];                       // first-layer pre-add (bias / w_yx), unit half
    #pragma unroll
    for (int ut=0;ut<4;++ut)
      #pragma unroll
      for (int r=0;r<4;++r)
        bsr[ut][r] = isY ? w_yx[(b0+bh)*128 + uh*64 + ut*16 + q*4 + r]
                         : tb1[uh*64 + ut*16 + q*4 + r];

    #pragma unroll 1
    for (int ti=0; ti<32; ++ti) {
      const int tile = bh*32 + ti;
      const int par = ti&1;
      const int p = p0 + tile*16 + c;

      // ---- B-frags: h direct from global (shared by both waves of the pair)
      half8 hb[4];
      if (H16) {
        const uint* hp = h16 + (size_t)p*64;
        #pragma unroll
        for (int kt=0;kt<4;++kt) hb[kt] = ld_h8(hp + kt*16 + q*4);
      } else {
        const float* hp = h_f32 + (size_t)p*128;
        #pragma unroll
        for (int kt=0;kt<4;++kt) {
          const float4* fp = (const float4*)(hp + kt*32 + q*8);
          float4 v0 = fp[0], v1 = fp[1];
          half8 hv;
          hv[0]=(_Float16)v0.x; hv[1]=(_Float16)v0.y; hv[2]=(_Float16)v0.z; hv[3]=(_Float16)v0.w;
          hv[4]=(_Float16)v1.x; hv[5]=(_Float16)v1.y; hv[6]=(_Float16)v1.z; hv[7]=(_Float16)v1.w;
          hb[kt] = hv;
        }
      }
      // H16: t-pair expands h -> f32 o_h (store-and-forget; wave uh stores kt 2uh,2uh+1)
      if (H16 && !isY) {
        float* op = o_h + (size_t)p*128;
        #pragma unroll
        for (int kk=0;kk<2;++kk) {
          const int kt = uh*2 + kk;
          float4 f0 = make_float4((float)hb[kt][0], (float)hb[kt][1], (float)hb[kt][2], (float)hb[kt][3]);
          float4 f1 = make_float4((float)hb[kt][4], (float)hb[kt][5], (float)hb[kt][6], (float)hb[kt][7]);
          *(float4*)(op + kt*32 + q*8)     = f0;
          *(float4*)(op + kt*32 + q*8 + 4) = f1;
        }
      }

      // ---- layer 1 (4 unit-tiles per wave)
      f32x4 acc[4];
      #pragma unroll
      for (int ut=0;ut<4;++ut) acc[ut] = bsr[ut];
      #pragma unroll
      for (int kt=0;kt<4;++kt)
        #pragma unroll
        for (int ut=0;ut<4;++ut) acc[ut] = MFMA(wf[ut*6+kt], hb[kt], acc[ut]);
      if (isY) {
        half8 eb[2];
        const int av = a[p], tv = tt[p];
        eb[0] = ld_h8(&s_al[av*20 + q*4]);
        if (q < 2) eb[1] = ld_h8(&s_te[tv*8 + q*4]);
        else {
          half8 z;
          #pragma unroll
          for (int j=0;j<8;++j) z[j] = (_Float16)0.f;
          eb[1] = z;
        }
        #pragma unroll
        for (int kt=4;kt<6;++kt)
          #pragma unroll
          for (int ut=0;ut<4;++ut) acc[ut] = MFMA(wf[ut*6+kt], eb[kt-4], acc[ut]);
      }

      // ---- gelu, pack into pair-shared double-buffered LDS
      #pragma unroll
      for (int ut=0;ut<4;++ut)
        #pragma unroll
        for (int pr=0;pr<2;++pr) {
          float g0 = gelu_exact(acc[ut][2*pr]);
          float g1 = gelu_exact(acc[ut][2*pr+1]);
          s_gb[pair][par][c*68 + uh*32 + ut*8 + 2*q + pr] = packh2(g0, g1);
        }
      wg_barrier();   // pair halves visible (lgkm-only; stores stay in flight)

      // ---- layer 2 (redundant within the pair; only wave uh==0 stores)
      f32x4 a2; a2[0]=0.f; a2[1]=0.f; a2[2]=0.f; a2[3]=0.f;
      #pragma unroll
      for (int kt=0;kt<4;++kt) {
        half8 gb = ld_h8(&s_gb[pair][par][c*68 + kt*16 + q*4]);
        a2 = MFMA(w2f[kt], gb, a2);
      }
      if (uh==0 && lane < 16) {
        if (!isY) {
          float4 o = make_float4(a2[0]+tb2r[0], a2[1]+tb2r[1], a2[2]+tb2r[2], a2[3]+tb2r[3]);
          *(float4*)&o_t[(size_t)p*4] = o;
        } else {
          o_y[p] = a2[0] + yb2s;
        }
      }
    }
  }
}

// ---------------------------------------------------------------------------
extern "C" void kernel_launch(void* const* d_in, const int* in_sizes, int n_in,
                              void* d_out, int out_size, void* d_ws, size_t ws_size,
                              hipStream_t stream) {
  (void)in_sizes; (void)n_in; (void)out_size;
  const float* x     = (const float*)d_in[0];
  const int*   a     = (const int*)  d_in[1];
  const int*   tt    = (const int*)  d_in[2];
  const float* y     = (const float*)d_in[3];
  const float* mask  = (const float*)d_in[4];
  const float* xW    = (const float*)d_in[5];
  const float* xb    = (const float*)d_in[6];
  const float* a_emb = (const float*)d_in[7];
  const float* t_emb = (const float*)d_in[8];
  const float* W_ih  = (const float*)d_in[9];
  const float* b_ih  = (const float*)d_in[10];
  const float* W_hh  = (const float*)d_in[11];
  const float* b_hh  = (const float*)d_in[12];
  const float* h0W   = (const float*)d_in[13];
  const float* h0b   = (const float*)d_in[14];
  const float* tW1   = (const float*)d_in[15];
  const float* tb1   = (const float*)d_in[16];
  const float* tW2   = (const float*)d_in[17];
  const float* tb2   = (const float*)d_in[18];
  const float* yW1   = (const float*)d_in[19];
  const float* yb1   = (const float*)d_in[20];
  const float* yW2   = (const float*)d_in[21];
  const float* yb2   = (const float*)d_in[22];

  float* o_y = (float*)d_out;                  // [B,S,1]   524288
  float* o_t = o_y + 524288;                   // [B,S,4]   2097152
  float* o_h = o_y + 2621440;                  // [B,S,128] 67108864

  float* ws    = (float*)d_ws;
  float* w_h0  = ws;                 // 131072
  float* w_xgx = ws + 131072;        // 393216
  float* w_yx  = ws + 524288;        // 131072

  // f16 h hand-off buffer if the workspace allows (134 MB)
  const size_t H16_BYTES = (size_t)524288 * 256;
  uint* h16 = nullptr;
  if (ws_size >= (size_t)655360*4 + H16_BYTES) h16 = (uint*)(ws + 655360);

  k_sample<<<1024, 384, 0, stream>>>(x, xW, xb, h0W, h0b, W_ih, b_ih, b_hh, yW1, yb1,
                                     w_h0, w_xgx, w_yx);
  k_recur<<<64, 384, 0, stream>>>(W_hh, W_ih, b_hh, a, tt, y, mask,
                                  w_h0, w_xgx, a_emb, t_emb, o_h, h16);
  if (h16)
    k_heads<true><<<512, 256, 0, stream>>>(tW1, tb1, tW2, tb2, yW1, yW2, yb2, a, tt,
                                           w_yx, a_emb, t_emb, o_h, h16, o_y, o_t, o_h);
  else
    k_heads<false><<<512, 256, 0, stream>>>(tW1, tb1, tW2, tb2, yW1, yW2, yb2, a, tt,
                                            w_yx, a_emb, t_emb, o_h, nullptr, o_y, o_t, o_h);
}

// Round 5
// 1194.064 us; speedup vs baseline: 1.1335x; 1.1335x over previous
//
#include <hip/hip_runtime.h>
#include <math.h>

#define SLEN 512

typedef _Float16 half8 __attribute__((ext_vector_type(8)));
typedef _Float16 half2v __attribute__((ext_vector_type(2)));
typedef __fp16 fp16x2 __attribute__((ext_vector_type(2)));
typedef float f32x4 __attribute__((ext_vector_type(4)));
typedef unsigned int uint;

union U4H8 { uint4 u; half8 h; };
union UH2 { uint u; half2v v; fp16x2 p; };

static __device__ __forceinline__ uint packh2(float a, float b){
  UH2 x; x.p = __builtin_amdgcn_cvt_pkrtz(a, b); return x.u;
}
static __device__ __forceinline__ float loh(uint u){ UH2 x; x.u=u; return (float)x.v[0]; }
static __device__ __forceinline__ float hih(uint u){ UH2 x; x.u=u; return (float)x.v[1]; }
static __device__ __forceinline__ half8 ld_h8(const uint* p){
  U4H8 x; x.u = *(const uint4*)p; return x.h;
}
static __device__ __forceinline__ float rcpf(float x){ return __builtin_amdgcn_rcpf(x); }
static __device__ __forceinline__ float sigm(float v){ return rcpf(1.0f+__expf(-v)); }
static __device__ __forceinline__ float tanh_f(float v){ return 1.0f - 2.0f*rcpf(__expf(2.0f*v)+1.0f); }
static __device__ __forceinline__ float gelu_exact(float v){
  return 0.5f*v*(1.0f+erff(v*0.7071067811865475f));
}
#define MFMA(a,b,c) __builtin_amdgcn_mfma_f32_16x16x32_f16((a),(b),(c),0,0,0)

// LDS-visibility-only workgroup barrier (no vmcnt drain, no sched pinning).
static __device__ __forceinline__ void wg_sync(){
  asm volatile("s_waitcnt lgkmcnt(0)" ::: "memory");
  __builtin_amdgcn_s_barrier();
}

// ---------------------------------------------------------------------------
// Per-sample precompute: x_enc -> h0[b,128], x_gx[b,384] (+b_ih, +b_hh r/z), yx[b,128] (+yb1)
// ---------------------------------------------------------------------------
__global__ void k_sample(const float* __restrict__ x, const float* __restrict__ xW, const float* __restrict__ xb,
                         const float* __restrict__ h0W, const float* __restrict__ h0b,
                         const float* __restrict__ W_ih, const float* __restrict__ b_ih, const float* __restrict__ b_hh,
                         const float* __restrict__ yW1, const float* __restrict__ yb1,
                         float* __restrict__ w_h0, float* __restrict__ w_xgx, float* __restrict__ w_yx)
{
  const int b = blockIdx.x, tid = threadIdx.x;   // 384 threads
  __shared__ float sx[128];
  __shared__ float sxe[128];
  if (tid < 128) sx[tid] = x[b*128+tid];
  __syncthreads();
  if (tid < 128) {
    float acc = xb[tid];
    #pragma unroll 8
    for (int j=0;j<128;++j) acc += xW[tid*128+j]*sx[j];
    sxe[tid] = acc;
  }
  __syncthreads();
  {
    const int o = tid;
    float acc = b_ih[o] + (o < 256 ? b_hh[o] : 0.f);   // fold b_hh for r,z only
    #pragma unroll 8
    for (int j=0;j<128;++j) acc += W_ih[o*177+j]*sxe[j];
    w_xgx[b*384+o] = acc;
  }
  if (tid < 128) {
    float acc = h0b[tid];
    #pragma unroll 8
    for (int j=0;j<128;++j) acc += h0W[tid*128+j]*sxe[j];
    w_h0[b*128+tid] = tanhf(acc);
    float a2 = yb1[tid];
    #pragma unroll 8
    for (int j=0;j<128;++j) a2 += yW1[tid*304+128+j]*sxe[j];
    w_yx[b*128+tid] = a2;
  }
}

// ---------------------------------------------------------------------------
// MFMA recurrence, ONE barrier per step. 64 WGs x 512 thr (8 waves), 16
// samples per WG. Wave wv owns h-rows [wv*16, wv*16+16) of ALL THREE gates:
// r,z,n for the same rows land in the same lanes -> the GRU combine is fully
// register-local (no s_rz, no s_ext, no second phase). Each wave gathers its
// ext B-frags from packed LDS tables and stores its own h(s) rows straight
// from registers to h16 (f16) or o_h (f32 fallback).
// ---------------------------------------------------------------------------
__global__ __launch_bounds__(512,1) void k_recur(
  const float* __restrict__ W_hh, const float* __restrict__ W_ih, const float* __restrict__ b_hh,
  const int* __restrict__ a, const int* __restrict__ tt,
  const float* __restrict__ yy, const float* __restrict__ mask,
  const float* __restrict__ w_h0, const float* __restrict__ w_xgx,
  const float* __restrict__ a_emb, const float* __restrict__ t_emb,
  float* __restrict__ o_h, uint* __restrict__ h16)
{
  const int tid = threadIdx.x;
  const int wv = tid>>6, lane = tid&63, q = lane>>4, c = lane&15;
  const int b0 = blockIdx.x*16;
  const int r0 = wv*16;                       // this wave's row tile (per gate)

  __shared__ __align__(16) uint s_h[2][16*68];     // h f16 [sample][k/2], pad
  __shared__ __align__(16) uint s_chunk[2][1024];  // [arr(a,t,y,m)][sample][16 steps]
  __shared__ __align__(16) uint s_al[1600];        // a_emb packed f16 [100][16]
  __shared__ __align__(16) uint s_te[32];          // t_emb packed f16 [4][8]

  // ---- stationary weight A-frags: wf[g*6+kt], g=0(r),1(z),2(n)
  half8 wf[18];
  #pragma unroll
  for (int g=0; g<3; ++g) {
    const int row = g*128 + r0 + c;
    #pragma unroll
    for (int kt=0; kt<4; ++kt) {
      const float4* wp = (const float4*)(W_hh + row*128 + kt*32 + q*8);
      float4 v0 = wp[0], v1 = wp[1];
      half8 hv;
      hv[0]=(_Float16)v0.x; hv[1]=(_Float16)v0.y; hv[2]=(_Float16)v0.z; hv[3]=(_Float16)v0.w;
      hv[4]=(_Float16)v1.x; hv[5]=(_Float16)v1.y; hv[6]=(_Float16)v1.z; hv[7]=(_Float16)v1.w;
      wf[g*6+kt] = hv;
    }
    #pragma unroll
    for (int kt=4; kt<6; ++kt) {
      half8 hv;
      #pragma unroll
      for (int j=0;j<8;++j) {
        int k2 = (kt-4)*32 + q*8 + j;
        float v = (k2 < 49) ? W_ih[row*177 + 128 + k2] : 0.f;
        hv[j] = (_Float16)v;
      }
      wf[g*6+kt] = hv;
    }
  }
  // per-lane state: 4 rows (r0 + q*4 + j) x sample c
  f32x4 xgr, xgz, xgn, bhh, hm;
  #pragma unroll
  for (int j=0;j<4;++j) {
    const int rr = r0 + q*4 + j;
    xgr[j] = w_xgx[(b0+c)*384 +       rr];
    xgz[j] = w_xgx[(b0+c)*384 + 128 + rr];
    xgn[j] = w_xgx[(b0+c)*384 + 256 + rr];
    bhh[j] = b_hh[256 + rr];
    hm[j]  = w_h0[(b0+c)*128 + rr];
  }
  // stage embedding tables (packed f16)
  for (int d = tid; d < 1600; d += 512) {
    int row = d>>4, col = d&15;
    s_al[d] = packh2(a_emb[row*32+2*col], a_emb[row*32+2*col+1]);
  }
  if (tid < 32) {
    int row = tid>>3, col = tid&7;
    s_te[tid] = packh2(t_emb[row*16+2*col], t_emb[row*16+2*col+1]);
  }
  // chunk 0 (wave 0): arr q: 0=a,1=t,2=y,3=mask ; 16 steps per sample
  uint4 cr0, cr1, cr2, cr3;
  if (wv==0) {
    const uint* bp = (q==0) ? (const uint*)a : (q==1) ? (const uint*)tt
                   : (q==2) ? (const uint*)yy : (const uint*)mask;
    const uint4* p = (const uint4*)(bp + (size_t)(b0+c)*512);
    cr0=p[0]; cr1=p[1]; cr2=p[2]; cr3=p[3];
    uint4* dst = (uint4*)&s_chunk[0][q*256 + c*16];
    dst[0]=cr0; dst[1]=cr1; dst[2]=cr2; dst[3]=cr3;
  }
  // h0 -> s_h[0] (each wave writes its rows)
  s_h[0][c*68 + wv*8 + q*2]     = packh2(hm[0], hm[1]);
  s_h[0][c*68 + wv*8 + q*2 + 1] = packh2(hm[2], hm[3]);
  __syncthreads();

  for (int s=0; s<SLEN; ++s) {
    const int pb = s&1, par = (s>>4)&1, st = s&15;
    // ---- B-frags: h
    half8 hb[4];
    #pragma unroll
    for (int kt=0;kt<4;++kt) hb[kt] = ld_h8(&s_h[pb][c*68 + kt*16 + q*4]);
    // ---- ext B-frags gathered per wave
    const int av = (int)s_chunk[par][c*16 + st];
    const int tv = (int)s_chunk[par][256 + c*16 + st];
    const float yv = __uint_as_float(s_chunk[par][512 + c*16 + st]);
    const float mval = __uint_as_float(s_chunk[par][768 + c*16 + st]);
    half8 eb0 = ld_h8(&s_al[av*16 + q*4]);
    half8 eb1;
    if (q < 2) eb1 = ld_h8(&s_te[tv*8 + q*4]);
    else { U4H8 t; t.u = make_uint4((q==2)?packh2(yv,0.f):0u,0u,0u,0u); eb1 = t.h; }
    // ---- store h(s) (pre-update state) straight from registers
    {
      const size_t p = (size_t)(b0+c)*SLEN + s;
      if (h16) {
        uint2 u; u.x = packh2(hm[0], hm[1]); u.y = packh2(hm[2], hm[3]);
        *(uint2*)(h16 + p*64 + wv*8 + q*2) = u;
      } else {
        *(float4*)(o_h + p*128 + r0 + q*4) = make_float4(hm[0],hm[1],hm[2],hm[3]);
      }
    }
    // ---- 18 MFMA: r(6), z(6), n_h(4), n_x(2)
    f32x4 ar = xgr, az = xgz, anh = bhh, anx = xgn;
    #pragma unroll
    for (int kt=0;kt<4;++kt) {
      ar  = MFMA(wf[kt],      hb[kt], ar);
      az  = MFMA(wf[6+kt],    hb[kt], az);
      anh = MFMA(wf[12+kt],   hb[kt], anh);
    }
    ar  = MFMA(wf[4],  eb0, ar);   ar  = MFMA(wf[5],  eb1, ar);
    az  = MFMA(wf[10], eb0, az);   az  = MFMA(wf[11], eb1, az);
    anx = MFMA(wf[16], eb0, anx);  anx = MFMA(wf[17], eb1, anx);
    // ---- register-local GRU combine
    #pragma unroll
    for (int j=0;j<4;++j) {
      float rj = sigm(ar[j]), zj = sigm(az[j]);
      float nj = tanh_f(anx[j] + rj*anh[j]);
      float hn = nj + zj*(hm[j] - nj);
      hm[j] = hm[j] + mval*(hn - hm[j]);
    }
    // ---- write h(s+1) rows
    const int nb = (s+1)&1;
    s_h[nb][c*68 + wv*8 + q*2]     = packh2(hm[0], hm[1]);
    s_h[nb][c*68 + wv*8 + q*2 + 1] = packh2(hm[2], hm[3]);
    // ---- chunk prefetch (wave 0)
    if (wv==0) {
      if ((st)==8 && s<490) {
        const int s0n = ((s>>4)+1)*16;
        const uint* bp = (q==0) ? (const uint*)a : (q==1) ? (const uint*)tt
                       : (q==2) ? (const uint*)yy : (const uint*)mask;
        const uint4* p = (const uint4*)(bp + (size_t)(b0+c)*512 + s0n);
        cr0=p[0]; cr1=p[1]; cr2=p[2]; cr3=p[3];
      }
      if ((st)==9 && s<491) {
        uint4* dst = (uint4*)&s_chunk[((s>>4)+1)&1][q*256 + c*16];
        dst[0]=cr0; dst[1]=cr1; dst[2]=cr2; dst[3]=cr3;
      }
    }
    wg_sync();   // ONE barrier per step (lgkm-only)
  }
}

// ---------------------------------------------------------------------------
// MFMA heads, wave-pair unit-split + software pipeline. 512 WGs x 256 thr.
// Waves {0,1} = t-head, {2,3} = y-head; wave wv&1 owns 4 of 8 unit-tiles
// (wf[24] = 96 VGPRs, no spill). Next tile's h/a/t loads are issued BEFORE
// the per-tile lgkm-only barrier, so they fly during barrier+layer2.
// Layer-2 deduped: wave uh handles tiles with ti&1==uh.
// ---------------------------------------------------------------------------
template<bool H16>
__global__ __launch_bounds__(256,2) void k_heads(
  const float* __restrict__ tW1, const float* __restrict__ tb1,
  const float* __restrict__ tW2, const float* __restrict__ tb2,
  const float* __restrict__ yW1, const float* __restrict__ yW2, const float* __restrict__ yb2,
  const int* __restrict__ a, const int* __restrict__ tt,
  const float* __restrict__ w_yx,
  const float* __restrict__ a_emb, const float* __restrict__ t_emb,
  const float* __restrict__ h_f32, const uint* __restrict__ h16,
  float* __restrict__ o_y, float* __restrict__ o_t, float* __restrict__ o_h)
{
  const int tid = threadIdx.x;
  const int wv = tid>>6, lane = tid&63, q = lane>>4, c = lane&15;
  const bool isY = (wv >= 2);
  const int uh = wv&1;          // unit half (0: units 0-63, 1: 64-127)
  const int pair = wv>>1;       // 0 = t-head pair, 1 = y-head pair
  const int p0 = blockIdx.x*1024;
  const int b0 = blockIdx.x*2;

  __shared__ __align__(16) uint s_al[100*20];      // a_emb packed f16, stride 20
  __shared__ __align__(16) uint s_te[32];          // t_emb packed f16 [4][8]
  __shared__ __align__(16) uint s_gb[2][2][16*68]; // [pair][parity][c*68 + word]

  for (int d = tid; d < 1600; d += 256) {
    int row = d>>4, col = d&15;
    s_al[row*20+col] = packh2(a_emb[row*32+2*col], a_emb[row*32+2*col+1]);
  }
  if (tid < 32) {
    int row = tid>>3, col = tid&7;
    s_te[row*8+col] = packh2(t_emb[row*16+2*col], t_emb[row*16+2*col+1]);
  }

  // ---- stationary first-layer weights: wf[ut*6+kt], unit = uh*64 + ut*16 + c
  half8 wf[24];
  const float* W1 = isY ? yW1 : tW1;
  const int w1stride = isY ? 304 : 128;
  #pragma unroll
  for (int ut=0;ut<4;++ut) {
    const int unit = uh*64 + ut*16 + c;
    #pragma unroll
    for (int kt=0;kt<4;++kt) {
      const float4* wp = (const float4*)(W1 + unit*w1stride + kt*32 + q*8);
      float4 v0 = wp[0], v1 = wp[1];
      half8 hv;
      hv[0]=(_Float16)v0.x; hv[1]=(_Float16)v0.y; hv[2]=(_Float16)v0.z; hv[3]=(_Float16)v0.w;
      hv[4]=(_Float16)v1.x; hv[5]=(_Float16)v1.y; hv[6]=(_Float16)v1.z; hv[7]=(_Float16)v1.w;
      wf[ut*6+kt] = hv;
    }
    #pragma unroll
    for (int kt=4;kt<6;++kt) {
      half8 hv;
      #pragma unroll
      for (int j=0;j<8;++j) {
        int k2 = (kt-4)*32 + q*8 + j;
        float v = (isY && k2 < 48) ? yW1[unit*304 + 256 + k2] : 0.f;
        hv[j] = (_Float16)v;
      }
      wf[ut*6+kt] = hv;
    }
  }
  // ---- second-layer A-frags
  half8 w2f[4];
  #pragma unroll
  for (int kt=0;kt<4;++kt) {
    half8 hv;
    #pragma unroll
    for (int j=0;j<8;++j) {
      float v = 0.f;
      if (!isY && c < 4) v = tW2[c*128 + kt*32 + q*8 + j];
      if ( isY && c == 0) v = yW2[kt*32 + q*8 + j];
      hv[j] = (_Float16)v;
    }
    w2f[kt] = hv;
  }
  float tb2r[4]; float yb2s = yb2[0];
  #pragma unroll
  for (int r=0;r<4;++r) tb2r[r] = tb2[r];
  // first-layer pre-adds for both samples of this WG
  f32x4 bsr0[4], bsr1[4];
  #pragma unroll
  for (int ut=0;ut<4;++ut)
    #pragma unroll
    for (int r=0;r<4;++r) {
      const int u = uh*64 + ut*16 + q*4 + r;
      bsr0[ut][r] = isY ? w_yx[(b0+0)*128 + u] : tb1[u];
      bsr1[ut][r] = isY ? w_yx[(b0+1)*128 + u] : tb1[u];
    }

  __syncthreads();

  // ---- preload tile 0
  half8 hbn[4];
  int avn = 0, tvn = 0;
  if (H16) {
    const uint* hp = h16 + (size_t)(p0 + c)*64;
    #pragma unroll
    for (int kt=0;kt<4;++kt) hbn[kt] = ld_h8(hp + kt*16 + q*4);
  }
  if (isY) { avn = a[p0 + c]; tvn = tt[p0 + c]; }

  #pragma unroll 1
  for (int ti=0; ti<64; ++ti) {
    const int par = ti&1;
    const int p = p0 + ti*16 + c;

    // ---- current tile B-frags
    half8 hb[4];
    if (H16) {
      #pragma unroll
      for (int kt=0;kt<4;++kt) hb[kt] = hbn[kt];
    } else {
      const float* hp = h_f32 + (size_t)p*128;
      #pragma unroll
      for (int kt=0;kt<4;++kt) {
        const float4* fp = (const float4*)(hp + kt*32 + q*8);
        float4 v0 = fp[0], v1 = fp[1];
        half8 hv;
        hv[0]=(_Float16)v0.x; hv[1]=(_Float16)v0.y; hv[2]=(_Float16)v0.z; hv[3]=(_Float16)v0.w;
        hv[4]=(_Float16)v1.x; hv[5]=(_Float16)v1.y; hv[6]=(_Float16)v1.z; hv[7]=(_Float16)v1.w;
        hb[kt] = hv;
      }
    }
    const int av = avn, tv = tvn;

    // H16: t-pair expands h -> f32 o_h (store-and-forget; wave uh stores kt 2uh,2uh+1)
    if (H16 && !isY) {
      float* op = o_h + (size_t)p*128;
      #pragma unroll
      for (int kk=0;kk<2;++kk) {
        const int kt = uh*2 + kk;
        float4 f0 = make_float4((float)hb[kt][0], (float)hb[kt][1], (float)hb[kt][2], (float)hb[kt][3]);
        float4 f1 = make_float4((float)hb[kt][4], (float)hb[kt][5], (float)hb[kt][6], (float)hb[kt][7]);
        *(float4*)(op + kt*32 + q*8)     = f0;
        *(float4*)(op + kt*32 + q*8 + 4) = f1;
      }
    }

    // ---- layer 1 (4 unit-tiles per wave)
    f32x4 acc[4];
    #pragma unroll
    for (int ut=0;ut<4;++ut) acc[ut] = (ti < 32) ? bsr0[ut] : bsr1[ut];
    #pragma unroll
    for (int kt=0;kt<4;++kt)
      #pragma unroll
      for (int ut=0;ut<4;++ut) acc[ut] = MFMA(wf[ut*6+kt], hb[kt], acc[ut]);
    if (isY) {
      half8 eb[2];
      eb[0] = ld_h8(&s_al[av*20 + q*4]);
      if (q < 2) eb[1] = ld_h8(&s_te[tv*8 + q*4]);
      else {
        half8 z;
        #pragma unroll
        for (int j=0;j<8;++j) z[j] = (_Float16)0.f;
        eb[1] = z;
      }
      #pragma unroll
      for (int kt=4;kt<6;++kt)
        #pragma unroll
        for (int ut=0;ut<4;++ut) acc[ut] = MFMA(wf[ut*6+kt], eb[kt-4], acc[ut]);
    }

    // ---- gelu, pack into pair-shared double-buffered LDS
    #pragma unroll
    for (int ut=0;ut<4;++ut)
      #pragma unroll
      for (int pr=0;pr<2;++pr) {
        float g0 = gelu_exact(acc[ut][2*pr]);
        float g1 = gelu_exact(acc[ut][2*pr+1]);
        s_gb[pair][par][c*68 + uh*32 + ut*8 + 2*q + pr] = packh2(g0, g1);
      }

    // ---- prefetch next tile (issues before the barrier; no vmcnt drain)
    {
      const int tn = (ti < 63) ? ti+1 : 63;
      const int pn = p0 + tn*16 + c;
      if (H16) {
        const uint* hp = h16 + (size_t)pn*64;
        #pragma unroll
        for (int kt=0;kt<4;++kt) hbn[kt] = ld_h8(hp + kt*16 + q*4);
      }
      if (isY) { avn = a[pn]; tvn = tt[pn]; }
    }

    wg_sync();   // pair halves visible (lgkm-only)

    // ---- layer 2 (deduped: wave uh handles its parity)
    if (par == uh) {
      f32x4 a2; a2[0]=0.f; a2[1]=0.f; a2[2]=0.f; a2[3]=0.f;
      #pragma unroll
      for (int kt=0;kt<4;++kt) {
        half8 gb = ld_h8(&s_gb[pair][par][c*68 + kt*16 + q*4]);
        a2 = MFMA(w2f[kt], gb, a2);
      }
      if (lane < 16) {
        if (!isY) {
          float4 o = make_float4(a2[0]+tb2r[0], a2[1]+tb2r[1], a2[2]+tb2r[2], a2[3]+tb2r[3]);
          *(float4*)&o_t[(size_t)p*4] = o;
        } else {
          o_y[p] = a2[0] + yb2s;
        }
      }
    }
  }
}

// ---------------------------------------------------------------------------
extern "C" void kernel_launch(void* const* d_in, const int* in_sizes, int n_in,
                              void* d_out, int out_size, void* d_ws, size_t ws_size,
                              hipStream_t stream) {
  (void)in_sizes; (void)n_in; (void)out_size;
  const float* x     = (const float*)d_in[0];
  const int*   a     = (const int*)  d_in[1];
  const int*   tt    = (const int*)  d_in[2];
  const float* y     = (const float*)d_in[3];
  const float* mask  = (const float*)d_in[4];
  const float* xW    = (const float*)d_in[5];
  const float* xb    = (const float*)d_in[6];
  const float* a_emb = (const float*)d_in[7];
  const float* t_emb = (const float*)d_in[8];
  const float* W_ih  = (const float*)d_in[9];
  const float* b_ih  = (const float*)d_in[10];
  const float* W_hh  = (const float*)d_in[11];
  const float* b_hh  = (const float*)d_in[12];
  const float* h0W   = (const float*)d_in[13];
  const float* h0b   = (const float*)d_in[14];
  const float* tW1   = (const float*)d_in[15];
  const float* tb1   = (const float*)d_in[16];
  const float* tW2   = (const float*)d_in[17];
  const float* tb2   = (const float*)d_in[18];
  const float* yW1   = (const float*)d_in[19];
  const float* yb1   = (const float*)d_in[20];
  const float* yW2   = (const float*)d_in[21];
  const float* yb2   = (const float*)d_in[22];

  float* o_y = (float*)d_out;                  // [B,S,1]   524288
  float* o_t = o_y + 524288;                   // [B,S,4]   2097152
  float* o_h = o_y + 2621440;                  // [B,S,128] 67108864

  float* ws    = (float*)d_ws;
  float* w_h0  = ws;                 // 131072
  float* w_xgx = ws + 131072;        // 393216
  float* w_yx  = ws + 524288;        // 131072

  // f16 h hand-off buffer if the workspace allows (134 MB)
  const size_t H16_BYTES = (size_t)524288 * 256;
  uint* h16 = nullptr;
  if (ws_size >= (size_t)655360*4 + H16_BYTES) h16 = (uint*)(ws + 655360);

  k_sample<<<1024, 384, 0, stream>>>(x, xW, xb, h0W, h0b, W_ih, b_ih, b_hh, yW1, yb1,
                                     w_h0, w_xgx, w_yx);
  k_recur<<<64, 512, 0, stream>>>(W_hh, W_ih, b_hh, a, tt, y, mask,
                                  w_h0, w_xgx, a_emb, t_emb, o_h, h16);
  if (h16)
    k_heads<true><<<512, 256, 0, stream>>>(tW1, tb1, tW2, tb2, yW1, yW2, yb2, a, tt,
                                           w_yx, a_emb, t_emb, o_h, h16, o_y, o_t, o_h);
  else
    k_heads<false><<<512, 256, 0, stream>>>(tW1, tb1, tW2, tb2, yW1, yW2, yb2, a, tt,
                                            w_yx, a_emb, t_emb, o_h, nullptr, o_y, o_t, o_h);
}